// Round 5
// baseline (184.850 us; speedup 1.0000x reference)
//
#include <hip/hip_runtime.h>
#include <stdint.h>

#define A_NUM 9
#define H_FM 50
#define W_FM 80
#define N_ANCH (A_NUM * H_FM * W_FM)   // 36000
#define PRE_NMS_N 6000
#define POST_NMS_N 300
#define NMS_TH 0.7f
#define MASK_W 94            // ceil(6000/64)
#define MASK_STRIDE 96
#define NBIN 4096

typedef unsigned long long ull;

// base anchor widths/heights (verified vs generate_anchors with np.round half-to-even)
__constant__ float c_aw[9] = {184.f,368.f,736.f,128.f,256.f,512.f, 88.f,176.f,352.f};
__constant__ float c_ah[9] = { 96.f,192.f,384.f,128.f,256.f,512.f,176.f,352.f,704.f};

__device__ float4 g_boxes[N_ANCH];
__device__ ull    g_keys[N_ANCH];
__device__ ull    g_bkeys[N_ANCH];         // bin-bucketed keys
__device__ int    g_base[NBIN + 1];        // exclusive bin bases (= global rank offsets)
__device__ int    g_cand_end;              // end slot of boundary bin
__device__ float4 g_props[PRE_NMS_N];
__device__ ull    g_mask[(size_t)PRE_NMS_N * MASK_STRIDE];
__device__ ull    g_colsup[MASK_W * 64];   // in-word column suppressor masks
__device__ ull    g_dead[MASK_STRIDE];
__device__ ull    g_rowany[MASK_STRIDE];

// ---------------- decode + key build ----------------
__global__ void k_decode(const float* __restrict__ scores,
                         const float* __restrict__ deltas,
                         const float* __restrict__ iminfo) {
    int i = blockIdx.x * blockDim.x + threadIdx.x;
    if (i >= N_ANCH) return;

    int a    = i % A_NUM;
    int cell = i / A_NUM;
    int x    = cell % W_FM;
    int y    = cell / W_FM;
    const int hw = H_FM * W_FM;

    float sc = scores[(A_NUM + a) * hw + cell];

    int dbase = (a * 4) * hw + cell;
    float d0 = deltas[dbase];
    float d1 = deltas[dbase + hw];
    float d2 = deltas[dbase + 2 * hw];
    float d3 = deltas[dbase + 3 * hw];
    d2 = fminf(fmaxf(d2, -10.f), 10.f);
    d3 = fminf(fmaxf(d3, -10.f), 10.f);

    float aw = c_aw[a], ah = c_ah[a];
    float acx = (float)(x * 16 + 8);
    float acy = (float)(y * 16 + 8);

    float pcx = d0 * aw + acx;
    float pcy = d1 * ah + acy;
    float pw  = expf(d2) * aw;
    float ph  = expf(d3) * ah;

    float x1 = pcx - 0.5f * pw;
    float y1 = pcy - 0.5f * ph;
    float x2 = pcx + 0.5f * pw;
    float y2 = pcy + 0.5f * ph;

    float imh = iminfo[0], imw = iminfo[1], ims = iminfo[2];
    x1 = fminf(fmaxf(x1, 0.f), imw - 1.f);
    y1 = fminf(fmaxf(y1, 0.f), imh - 1.f);
    x2 = fminf(fmaxf(x2, 0.f), imw - 1.f);
    y2 = fminf(fmaxf(y2, 0.f), imh - 1.f);

    float wsz = x2 - x1 + 1.f;
    float hsz = y2 - y1 + 1.f;
    float minsz = 16.f * ims;
    bool valid = (wsz >= minsz) && (hsz >= minsz);

    g_boxes[i] = make_float4(x1, y1, x2, y2);

    unsigned int u   = __float_as_uint(sc);
    unsigned int asc = (u & 0x80000000u) ? ~u : (u | 0x80000000u);
    unsigned int dk  = ~asc;                 // ascending dk == descending score
    if (!valid) dk = 0xFF800000u;            // == key of -inf score (bin 4088)
    g_keys[i] = ((ull)dk << 32) | (unsigned int)i;
}

// ---------------- single-block histogram + prefix + counting scatter ----------------
__global__ __launch_bounds__(1024) void k_select() {
    __shared__ int h[NBIN];        // 16 KB: counts, then running scatter offsets
    __shared__ int ps[1024];
    __shared__ int sh_nvalid;
    int t = threadIdx.x;

    if (t < MASK_STRIDE) { g_dead[t] = 0ULL; g_rowany[t] = 0ULL; }
    for (int b = t; b < NBIN; b += 1024) h[b] = 0;
    __syncthreads();

    for (int i = t; i < N_ANCH; i += 1024)
        atomicAdd(&h[(int)(g_keys[i] >> 52)], 1);
    __syncthreads();

    // exclusive prefix over 4096 bins (4 per thread + Hillis-Steele over 1024)
    int a0 = h[4 * t], a1 = h[4 * t + 1], a2 = h[4 * t + 2], a3 = h[4 * t + 3];
    int s = a0 + a1 + a2 + a3;
    ps[t] = s;
    __syncthreads();
    for (int off = 1; off < 1024; off <<= 1) {
        int v = (t >= off) ? ps[t - off] : 0;
        __syncthreads();
        ps[t] += v;
        __syncthreads();
    }
    int incl = ps[t];
    int excl = incl - s;
    int b0 = excl, b1 = excl + a0, b2 = b1 + a1, b3 = b2 + a2;
    g_base[4 * t] = b0; g_base[4 * t + 1] = b1;
    g_base[4 * t + 2] = b2; g_base[4 * t + 3] = b3;
    if (t == 1023) g_base[NBIN] = incl;

    // boundary bin: base <= 5999 < end  -> candidates = slots [0, end)
    if (b0 <= PRE_NMS_N - 1 && PRE_NMS_N - 1 < b1) g_cand_end = b1;
    if (b1 <= PRE_NMS_N - 1 && PRE_NMS_N - 1 < b2) g_cand_end = b2;
    if (b2 <= PRE_NMS_N - 1 && PRE_NMS_N - 1 < b3) g_cand_end = b3;
    if (b3 <= PRE_NMS_N - 1 && PRE_NMS_N - 1 < incl) g_cand_end = incl;

    // invalid (-inf) elements all land in bin 4088 (owned by t=1022, slot a0)
    if (t == 1022) sh_nvalid = N_ANCH - a0;

    // reuse h as running scatter offsets (= bases)
    h[4 * t] = b0; h[4 * t + 1] = b1; h[4 * t + 2] = b2; h[4 * t + 3] = b3;
    __syncthreads();

    int nv = sh_nvalid;
    for (int sd = nv + t; sd < PRE_NMS_N; sd += 1024)   // normally empty
        atomicOr(&g_dead[sd >> 6], 1ULL << (sd & 63));

    for (int i = t; i < N_ANCH; i += 1024) {
        ull k = g_keys[i];
        int slot = atomicAdd(&h[(int)(k >> 52)], 1);
        g_bkeys[slot] = k;
    }
}

// ---------------- exact rank within bin segment + props scatter ----------------
__global__ void k_rank() {
    int tid = blockIdx.x * blockDim.x + threadIdx.x;   // 8192 threads
    int ce = g_cand_end;
    for (int slot = tid; slot < ce; slot += 8192) {
        ull key = g_bkeys[slot];
        int bin = (int)(key >> 52);
        int s0 = g_base[bin], s1 = g_base[bin + 1];
        int r = s0;
        for (int s = s0; s < s1; ++s)
            r += (g_bkeys[s] < key) ? 1 : 0;
        if (r < PRE_NMS_N) {
            unsigned int idx = (unsigned int)key;
            g_props[r] = g_boxes[idx];
        }
    }
}

// ---------------- IoU suppression mask matrix + cross-word rowany ----------------
__global__ void k_mask() {
    __shared__ float4 sj[256];
    int tid = threadIdx.x;
    int jbase = blockIdx.x * 256;
    int jj = jbase + tid;
    sj[tid] = (jj < PRE_NMS_N) ? g_props[jj] : make_float4(0.f, 0.f, 0.f, 0.f);
    __syncthreads();

    int li = tid & 63;
    int wl = tid >> 6;                       // 0..3
    int i  = blockIdx.y * 64 + li;
    int w  = blockIdx.x * 4 + wl;
    if (i >= PRE_NMS_N || w >= MASK_W) return;

    float4 bi = g_props[i];
    float ai = (bi.z - bi.x + 1.f) * (bi.w - bi.y + 1.f);
    ull bits = 0;
    int jstart = w * 64;
    int lbase = jstart - jbase;              // 0,64,128,192
    for (int b = 0; b < 64; ++b) {
        int j = jstart + b;
        if (j <= i || j >= PRE_NMS_N) continue;
        float4 bj = sj[lbase + b];
        float aj = (bj.z - bj.x + 1.f) * (bj.w - bj.y + 1.f);
        float iw = fminf(bi.z, bj.z) - fmaxf(bi.x, bj.x) + 1.f;
        float ih = fminf(bi.w, bj.w) - fmaxf(bi.y, bj.y) + 1.f;
        iw = fmaxf(iw, 0.f);
        ih = fmaxf(ih, 0.f);
        float inter = iw * ih;
        float iou = inter / (ai + aj - inter);
        if (iou > NMS_TH) bits |= (1ULL << b);
    }
    g_mask[(size_t)i * MASK_STRIDE + w] = bits;
    // rowany: only CROSS-word suppression (in-word is handled by colsup)
    if (bits && w != (i >> 6)) atomicOr(&g_rowany[i >> 6], 1ULL << (i & 63));
}

// ---------------- in-word column suppressor masks ----------------
__global__ void k_colsup() {
    __shared__ float4 sb[64];
    int w = blockIdx.x;      // 0..93
    int j = threadIdx.x;     // 0..63
    int gj = w * 64 + j;
    float4 bj = (gj < PRE_NMS_N) ? g_props[gj] : make_float4(0.f, 0.f, 0.f, 0.f);
    sb[j] = bj;
    __syncthreads();
    float aj = (bj.z - bj.x + 1.f) * (bj.w - bj.y + 1.f);
    ull bits = 0;
    for (int b = 0; b < j; ++b) {
        float4 bi = sb[b];
        float ai = (bi.z - bi.x + 1.f) * (bi.w - bi.y + 1.f);
        float iw = fminf(bi.z, bj.z) - fmaxf(bi.x, bj.x) + 1.f;
        float ih = fminf(bi.w, bj.w) - fmaxf(bi.y, bj.y) + 1.f;
        iw = fmaxf(iw, 0.f);
        ih = fmaxf(ih, 0.f);
        float inter = iw * ih;
        float iou = inter / (ai + aj - inter);
        if (iou > NMS_TH) bits |= (1ULL << b);
    }
    g_colsup[gj] = bits;
}

// ---------------- greedy scan: dead-word skip + ballot fixed point ----------------
#define BATCH 16
__global__ __launch_bounds__(64, 1) void k_scan(float* __restrict__ out) {
    __shared__ int s_kept[POST_NMS_N];
    int lane = threadIdx.x;
    ull rm0 = g_dead[lane];                                // words 0..63
    ull rm1 = (lane < MASK_W - 64) ? g_dead[64 + lane] : ~0ULL;  // words 64..93
    if (lane == 29) rm1 |= 0xFFFF000000000000ULL;          // pad indices 6000..6015
    int kc = 0;

    for (;;) {
        ull avail0 = __ballot(~rm0 != 0ULL);
        ull avail1 = __ballot(~rm1 != 0ULL);   // lanes>=30 contribute 0 (rm1=~0)
        int w;
        if (avail0)      w = __ffsll(avail0) - 1;
        else if (avail1) w = 63 + __ffsll(avail1);
        else break;

        ull diag = g_colsup[(w << 6) + lane];              // L2, off the shfl chain
        ull raw  = g_rowany[w];
        ull curw = (w < 64) ? __shfl(rm0, w) : __shfl(rm1, w - 64);

        // intra-word greedy fixed point via ballots
        ull U = ~curw;
        ull K = 0;
        while (U) {
            ull UK = U | K;
            bool deadp = (diag & K)  != 0ULL;
            bool freep = (diag & UK) == 0ULL;
            ull nd = __ballot(deadp) & U;
            U &= ~nd;
            ull nk = __ballot(freep) & U;
            U &= ~nk;
            K |= nk;
            if (!nk && !nd) break;   // safety; cannot happen
        }

        int cnt  = __popcll(K);
        int take = min(cnt, POST_NMS_N - kc);
        if (K & (1ULL << lane)) {
            int pos = kc + __popcll(K & ((1ULL << lane) - 1ULL));
            if (pos < POST_NMS_N) s_kept[pos] = (w << 6) + lane;
        }
        kc += take;
        if (kc >= POST_NMS_N) break;

        // word fully decided -> mark processed
        if (w < 64) { if (lane == w)      rm0 = ~0ULL; }
        else        { if (lane == w - 64) rm1 = ~0ULL; }

        // batched parallel row-OR for kept rows with cross-word suppression
        ull need = K & raw;
        while (need) {
            int id[BATCH];
            int n = 0;
#pragma unroll
            for (int t2 = 0; t2 < BATCH; ++t2) {
                id[t2] = 0;
                if (need) { id[t2] = __ffsll(need) - 1; need &= need - 1; n = t2 + 1; }
            }
            ull v0[BATCH], v1[BATCH];
#pragma unroll
            for (int t2 = 0; t2 < BATCH; ++t2) {
                const ull* __restrict__ row =
                    g_mask + (size_t)((w << 6) + id[t2]) * MASK_STRIDE;
                v0[t2] = row[lane];
                v1[t2] = (lane < MASK_W - 64) ? row[64 + lane] : 0ULL;
            }
            ull a0 = 0, a1 = 0;
#pragma unroll
            for (int t2 = 0; t2 < BATCH; ++t2) {
                ull m = (t2 < n) ? ~0ULL : 0ULL;
                a0 |= v0[t2] & m;
                a1 |= v1[t2] & m;
            }
            rm0 |= a0;
            rm1 |= a1;
        }
    }

    int kcf = (kc < POST_NMS_N) ? kc : POST_NMS_N;
    __syncthreads();
    for (int r = lane; r < POST_NMS_N; r += 64) {
        float4 p = make_float4(0.f, 0.f, 0.f, 0.f);
        if (r < kcf) p = g_props[s_kept[r]];
        out[r * 5 + 0] = 0.f;
        out[r * 5 + 1] = p.x;
        out[r * 5 + 2] = p.y;
        out[r * 5 + 3] = p.z;
        out[r * 5 + 4] = p.w;
    }
}

extern "C" void kernel_launch(void* const* d_in, const int* in_sizes, int n_in,
                              void* d_out, int out_size, void* d_ws, size_t ws_size,
                              hipStream_t stream) {
    const float* scores = (const float*)d_in[0];
    const float* deltas = (const float*)d_in[1];
    const float* iminfo = (const float*)d_in[2];
    float* out = (float*)d_out;

    k_decode<<<(N_ANCH + 255) / 256, 256, 0, stream>>>(scores, deltas, iminfo);
    k_select<<<1, 1024, 0, stream>>>();
    k_rank<<<32, 256, 0, stream>>>();
    k_colsup<<<MASK_W, 64, 0, stream>>>();
    k_mask<<<dim3(24, 94), 256, 0, stream>>>();
    k_scan<<<1, 64, 0, stream>>>(out);
}

// Round 6
// 151.801 us; speedup vs baseline: 1.2177x; 1.2177x over previous
//
#include <hip/hip_runtime.h>
#include <stdint.h>

#define A_NUM 9
#define H_FM 50
#define W_FM 80
#define N_ANCH (A_NUM * H_FM * W_FM)   // 36000
#define PRE_NMS_N 6000
#define POST_NMS_N 300
#define NMS_TH 0.7f
#define MASK_W 94            // ceil(6000/64)
#define MASK_STRIDE 96
#define NBIN 4096
#define NSORTK 8192

typedef unsigned long long ull;

// base anchor widths/heights (verified vs generate_anchors with np.round half-to-even)
__constant__ float c_aw[9] = {184.f,368.f,736.f,128.f,256.f,512.f, 88.f,176.f,352.f};
__constant__ float c_ah[9] = { 96.f,192.f,384.f,128.f,256.f,512.f,176.f,352.f,704.f};

__device__ float4 g_boxes[N_ANCH];
__device__ ull    g_keys[N_ANCH];
__device__ ull    g_bkeys[N_ANCH];         // bin-bucketed keys (fallback path only)
__device__ float4 g_props[PRE_NMS_N];
__device__ ull    g_mask[(size_t)PRE_NMS_N * MASK_STRIDE];
__device__ ull    g_colsup[MASK_W * 64];   // in-word column suppressor masks
__device__ ull    g_dead[MASK_STRIDE];
__device__ ull    g_rowany[MASK_STRIDE];

// ---------------- decode + key build ----------------
__global__ void k_decode(const float* __restrict__ scores,
                         const float* __restrict__ deltas,
                         const float* __restrict__ iminfo) {
    int i = blockIdx.x * blockDim.x + threadIdx.x;
    if (i >= N_ANCH) return;

    int a    = i % A_NUM;
    int cell = i / A_NUM;
    int x    = cell % W_FM;
    int y    = cell / W_FM;
    const int hw = H_FM * W_FM;

    float sc = scores[(A_NUM + a) * hw + cell];

    int dbase = (a * 4) * hw + cell;
    float d0 = deltas[dbase];
    float d1 = deltas[dbase + hw];
    float d2 = deltas[dbase + 2 * hw];
    float d3 = deltas[dbase + 3 * hw];
    d2 = fminf(fmaxf(d2, -10.f), 10.f);
    d3 = fminf(fmaxf(d3, -10.f), 10.f);

    float aw = c_aw[a], ah = c_ah[a];
    float acx = (float)(x * 16 + 8);
    float acy = (float)(y * 16 + 8);

    float pcx = d0 * aw + acx;
    float pcy = d1 * ah + acy;
    float pw  = expf(d2) * aw;
    float ph  = expf(d3) * ah;

    float x1 = pcx - 0.5f * pw;
    float y1 = pcy - 0.5f * ph;
    float x2 = pcx + 0.5f * pw;
    float y2 = pcy + 0.5f * ph;

    float imh = iminfo[0], imw = iminfo[1], ims = iminfo[2];
    x1 = fminf(fmaxf(x1, 0.f), imw - 1.f);
    y1 = fminf(fmaxf(y1, 0.f), imh - 1.f);
    x2 = fminf(fmaxf(x2, 0.f), imw - 1.f);
    y2 = fminf(fmaxf(y2, 0.f), imh - 1.f);

    float wsz = x2 - x1 + 1.f;
    float hsz = y2 - y1 + 1.f;
    float minsz = 16.f * ims;
    bool valid = (wsz >= minsz) && (hsz >= minsz);

    g_boxes[i] = make_float4(x1, y1, x2, y2);

    unsigned int u   = __float_as_uint(sc);
    unsigned int asc = (u & 0x80000000u) ? ~u : (u | 0x80000000u);
    unsigned int dk  = ~asc;                 // ascending dk == descending score
    if (!valid) dk = 0xFF800000u;            // == key of -inf score
    g_keys[i] = ((ull)dk << 32) | (unsigned int)i;
}

// ------- single-block: histogram + prefix + scatter-to-LDS + bitonic sort -------
// Exact top-6000 with full-u64 tie-break; writes g_props[rank] directly.
__global__ __launch_bounds__(1024) void k_select() {
    __shared__ int h[NBIN];            // 16 KB: counts -> running scatter offsets -> bin ends
    __shared__ ull skeys[NSORTK];      // 64 KB candidate keys
    __shared__ int sh_ce;
    int* ps = (int*)skeys;             // prefix-scan scratch overlaid on skeys (pre-scatter)
    int t = threadIdx.x;

    if (t < MASK_STRIDE) { g_dead[t] = 0ULL; g_rowany[t] = 0ULL; }
    for (int b = t; b < NBIN; b += 1024) h[b] = 0;
    __syncthreads();

    for (int i = t; i < N_ANCH; i += 1024)
        atomicAdd(&h[(int)(g_keys[i] >> 52)], 1);
    __syncthreads();

    // exclusive prefix over 4096 bins (4 per thread + Hillis-Steele over 1024)
    int a0 = h[4 * t], a1 = h[4 * t + 1], a2 = h[4 * t + 2], a3 = h[4 * t + 3];
    int s = a0 + a1 + a2 + a3;
    ps[t] = s;
    __syncthreads();
    for (int off = 1; off < 1024; off <<= 1) {
        int v = (t >= off) ? ps[t - off] : 0;
        __syncthreads();
        ps[t] += v;
        __syncthreads();
    }
    int incl = ps[t];
    int excl = incl - s;
    int b0 = excl, b1 = excl + a0, b2 = b1 + a1, b3 = b2 + a2;

    // boundary bin end: smallest bin-end > 5999 -> candidates = slots [0, ce)
    if (b0 <= PRE_NMS_N - 1 && PRE_NMS_N - 1 < b1)   sh_ce = b1;
    if (b1 <= PRE_NMS_N - 1 && PRE_NMS_N - 1 < b2)   sh_ce = b2;
    if (b2 <= PRE_NMS_N - 1 && PRE_NMS_N - 1 < b3)   sh_ce = b3;
    if (b3 <= PRE_NMS_N - 1 && PRE_NMS_N - 1 < incl) sh_ce = incl;
    __syncthreads();

    // running scatter offsets
    h[4 * t] = b0; h[4 * t + 1] = b1; h[4 * t + 2] = b2; h[4 * t + 3] = b3;
    __syncthreads();

    int ce = sh_ce;
    bool fits = (ce <= NSORTK);

    for (int i = t; i < N_ANCH; i += 1024) {
        ull k = g_keys[i];
        int slot = atomicAdd(&h[(int)(k >> 52)], 1);
        if (fits) { if (slot < NSORTK) skeys[slot] = k; }
        else      { g_bkeys[slot] = k; }
    }
    __syncthreads();
    // h[bin] now == exclusive end of bin

    if (fits) {
        for (int s2 = ce + t; s2 < NSORTK; s2 += 1024) skeys[s2] = ~0ULL;

        // bitonic sort 8192 keys, 4 compare-exchanges per thread per substage
        for (int k2 = 2; k2 <= NSORTK; k2 <<= 1) {
            for (int j = k2 >> 1; j >= 1; j >>= 1) {
                __syncthreads();
#pragma unroll
                for (int q = 0; q < 4; ++q) {
                    int p  = t + q * 1024;                       // pair id
                    int i  = ((p & ~(j - 1)) << 1) | (p & (j - 1));
                    int pr = i | j;
                    bool up = ((i & k2) == 0);
                    ull a = skeys[i], b = skeys[pr];
                    if ((a > b) == up) { skeys[i] = b; skeys[pr] = a; }
                }
            }
        }
        __syncthreads();

        for (int r = t; r < PRE_NMS_N; r += 1024) {
            ull key = skeys[r];
            unsigned int dk = (unsigned int)(key >> 32);
            if (dk < 0xFF800000u) {
                g_props[r] = g_boxes[(unsigned int)key];
            } else {
                g_props[r] = make_float4(0.f, 0.f, 0.f, 0.f);
                atomicOr(&g_dead[r >> 6], 1ULL << (r & 63));
            }
        }
    } else {
        // cold fallback (boundary bin overflow): exact counting rank off global
        for (int slot = t; slot < ce; slot += 1024) {
            ull key = ((volatile ull*)g_bkeys)[slot];
            int bin = (int)(key >> 52);
            int s0 = (bin > 0) ? h[bin - 1] : 0;
            int s1 = h[bin];
            int r = s0;
            for (int s2 = s0; s2 < s1; ++s2)
                r += (((volatile ull*)g_bkeys)[s2] < key) ? 1 : 0;
            if (r < PRE_NMS_N) {
                unsigned int dk = (unsigned int)(key >> 32);
                if (dk < 0xFF800000u) {
                    g_props[r] = g_boxes[(unsigned int)key];
                } else {
                    g_props[r] = make_float4(0.f, 0.f, 0.f, 0.f);
                    atomicOr(&g_dead[r >> 6], 1ULL << (r & 63));
                }
            }
        }
    }
}

// ---------------- IoU suppression mask matrix + cross-word rowany ----------------
__global__ void k_mask() {
    __shared__ float4 sj[256];
    int tid = threadIdx.x;
    int jbase = blockIdx.x * 256;
    int jj = jbase + tid;
    sj[tid] = (jj < PRE_NMS_N) ? g_props[jj] : make_float4(0.f, 0.f, 0.f, 0.f);
    __syncthreads();

    int li = tid & 63;
    int wl = tid >> 6;                       // 0..3
    int i  = blockIdx.y * 64 + li;
    int w  = blockIdx.x * 4 + wl;
    if (i >= PRE_NMS_N || w >= MASK_W) return;

    float4 bi = g_props[i];
    float ai = (bi.z - bi.x + 1.f) * (bi.w - bi.y + 1.f);
    ull bits = 0;
    int jstart = w * 64;
    int lbase = jstart - jbase;              // 0,64,128,192
    for (int b = 0; b < 64; ++b) {
        int j = jstart + b;
        if (j <= i || j >= PRE_NMS_N) continue;
        float4 bj = sj[lbase + b];
        float aj = (bj.z - bj.x + 1.f) * (bj.w - bj.y + 1.f);
        float iw = fminf(bi.z, bj.z) - fmaxf(bi.x, bj.x) + 1.f;
        float ih = fminf(bi.w, bj.w) - fmaxf(bi.y, bj.y) + 1.f;
        iw = fmaxf(iw, 0.f);
        ih = fmaxf(ih, 0.f);
        float inter = iw * ih;
        float iou = inter / (ai + aj - inter);
        if (iou > NMS_TH) bits |= (1ULL << b);
    }
    g_mask[(size_t)i * MASK_STRIDE + w] = bits;
    // rowany: only CROSS-word suppression (in-word is handled by colsup)
    if (bits && w != (i >> 6)) atomicOr(&g_rowany[i >> 6], 1ULL << (i & 63));
}

// ---------------- in-word column suppressor masks ----------------
__global__ void k_colsup() {
    __shared__ float4 sb[64];
    int w = blockIdx.x;      // 0..93
    int j = threadIdx.x;     // 0..63
    int gj = w * 64 + j;
    float4 bj = (gj < PRE_NMS_N) ? g_props[gj] : make_float4(0.f, 0.f, 0.f, 0.f);
    sb[j] = bj;
    __syncthreads();
    float aj = (bj.z - bj.x + 1.f) * (bj.w - bj.y + 1.f);
    ull bits = 0;
    for (int b = 0; b < j; ++b) {
        float4 bi = sb[b];
        float ai = (bi.z - bi.x + 1.f) * (bi.w - bi.y + 1.f);
        float iw = fminf(bi.z, bj.z) - fmaxf(bi.x, bj.x) + 1.f;
        float ih = fminf(bi.w, bj.w) - fmaxf(bi.y, bj.y) + 1.f;
        iw = fmaxf(iw, 0.f);
        ih = fmaxf(ih, 0.f);
        float inter = iw * ih;
        float iou = inter / (ai + aj - inter);
        if (iou > NMS_TH) bits |= (1ULL << b);
    }
    g_colsup[gj] = bits;
}

// ---------------- greedy scan: dead-word skip + ballot fixed point ----------------
#define BATCH 16
__global__ __launch_bounds__(64, 1) void k_scan(float* __restrict__ out) {
    __shared__ int s_kept[POST_NMS_N];
    int lane = threadIdx.x;
    ull rm0 = g_dead[lane];                                // words 0..63
    ull rm1 = (lane < MASK_W - 64) ? g_dead[64 + lane] : ~0ULL;  // words 64..93
    if (lane == 29) rm1 |= 0xFFFF000000000000ULL;          // pad indices 6000..6015
    int kc = 0;

    for (;;) {
        ull avail0 = __ballot(~rm0 != 0ULL);
        ull avail1 = __ballot(~rm1 != 0ULL);   // lanes>=30 contribute 0 (rm1=~0)
        int w;
        if (avail0)      w = __ffsll(avail0) - 1;
        else if (avail1) w = 63 + __ffsll(avail1);
        else break;

        ull diag = g_colsup[(w << 6) + lane];              // L2, off the shfl chain
        ull raw  = g_rowany[w];
        ull curw = (w < 64) ? __shfl(rm0, w) : __shfl(rm1, w - 64);

        // intra-word greedy fixed point via ballots
        ull U = ~curw;
        ull K = 0;
        while (U) {
            ull UK = U | K;
            bool deadp = (diag & K)  != 0ULL;
            bool freep = (diag & UK) == 0ULL;
            ull nd = __ballot(deadp) & U;
            U &= ~nd;
            ull nk = __ballot(freep) & U;
            U &= ~nk;
            K |= nk;
            if (!nk && !nd) break;   // safety; cannot happen
        }

        int cnt  = __popcll(K);
        int take = min(cnt, POST_NMS_N - kc);
        if (K & (1ULL << lane)) {
            int pos = kc + __popcll(K & ((1ULL << lane) - 1ULL));
            if (pos < POST_NMS_N) s_kept[pos] = (w << 6) + lane;
        }
        kc += take;
        if (kc >= POST_NMS_N) break;

        // word fully decided -> mark processed
        if (w < 64) { if (lane == w)      rm0 = ~0ULL; }
        else        { if (lane == w - 64) rm1 = ~0ULL; }

        // batched parallel row-OR for kept rows with cross-word suppression
        ull need = K & raw;
        while (need) {
            int id[BATCH];
            int n = 0;
#pragma unroll
            for (int t2 = 0; t2 < BATCH; ++t2) {
                id[t2] = 0;
                if (need) { id[t2] = __ffsll(need) - 1; need &= need - 1; n = t2 + 1; }
            }
            ull v0[BATCH], v1[BATCH];
#pragma unroll
            for (int t2 = 0; t2 < BATCH; ++t2) {
                const ull* __restrict__ row =
                    g_mask + (size_t)((w << 6) + id[t2]) * MASK_STRIDE;
                v0[t2] = row[lane];
                v1[t2] = (lane < MASK_W - 64) ? row[64 + lane] : 0ULL;
            }
            ull a0 = 0, a1 = 0;
#pragma unroll
            for (int t2 = 0; t2 < BATCH; ++t2) {
                ull m = (t2 < n) ? ~0ULL : 0ULL;
                a0 |= v0[t2] & m;
                a1 |= v1[t2] & m;
            }
            rm0 |= a0;
            rm1 |= a1;
        }
    }

    int kcf = (kc < POST_NMS_N) ? kc : POST_NMS_N;
    __syncthreads();
    for (int r = lane; r < POST_NMS_N; r += 64) {
        float4 p = make_float4(0.f, 0.f, 0.f, 0.f);
        if (r < kcf) p = g_props[s_kept[r]];
        out[r * 5 + 0] = 0.f;
        out[r * 5 + 1] = p.x;
        out[r * 5 + 2] = p.y;
        out[r * 5 + 3] = p.z;
        out[r * 5 + 4] = p.w;
    }
}

extern "C" void kernel_launch(void* const* d_in, const int* in_sizes, int n_in,
                              void* d_out, int out_size, void* d_ws, size_t ws_size,
                              hipStream_t stream) {
    const float* scores = (const float*)d_in[0];
    const float* deltas = (const float*)d_in[1];
    const float* iminfo = (const float*)d_in[2];
    float* out = (float*)d_out;

    k_decode<<<(N_ANCH + 255) / 256, 256, 0, stream>>>(scores, deltas, iminfo);
    k_select<<<1, 1024, 0, stream>>>();
    k_colsup<<<MASK_W, 64, 0, stream>>>();
    k_mask<<<dim3(24, 94), 256, 0, stream>>>();
    k_scan<<<1, 64, 0, stream>>>(out);
}